// Round 10
// baseline (234.029 us; speedup 1.0000x reference)
//
#include <hip/hip_runtime.h>
#include <hip/hip_fp16.h>

#define ND 100000   // N_NODES
#define NE 50000    // N_EDGES
#define AR 32       // EDGE_ARITY
#define DG 16       // NODE_DEG
#define D  128      // D_IN == D_OUT == TV

typedef _Float16 half8_t __attribute__((ext_vector_type(8)));
typedef _Float16 half4_t __attribute__((ext_vector_type(4)));
typedef float    f32x4_t __attribute__((ext_vector_type(4)));

#define APAD 136   // LDS A-row stride (halves): 16B-aligned, 2-way aliasing free
#define EPB 128    // edges per k_gather_e block (256 thr = 128 edges x 2 chunks)

// ---------------------------------------------------------------------------
// K0: fused prep.  blocks 0..63: w1,w2 -> fragment-major fp16.
//     block 64: inter_nw = mean(cos(w3 rows, w3[0])).
// ---------------------------------------------------------------------------
__global__ __launch_bounds__(256) void k_prep(const float* __restrict__ w1,
                                              const float* __restrict__ w2,
                                              const float* __restrict__ w3,
                                              _Float16* __restrict__ w1f,
                                              _Float16* __restrict__ w2f,
                                              float* __restrict__ inter_out) {
    if (blockIdx.x == 64) {
        __shared__ float red[128];
        int j = threadIdx.x;
        if (j < 128) {
            float dot = 0.f, sq = 0.f, sq0 = 0.f;
            #pragma unroll 8
            for (int k = 0; k < D; ++k) {
                float wj = w3[j * D + k];
                float w0 = w3[k];
                dot += wj * w0;
                sq  += wj * wj;
                sq0 += w0 * w0;
            }
            red[j] = dot / (sqrtf(sq0) * sqrtf(sq));
        }
        __syncthreads();
        if (j == 0) {
            float s = 0.f;
            for (int i = 0; i < 128; ++i) s += red[i];
            inter_out[0] = s / 128.f;
        }
        return;
    }
    int o = blockIdx.x * 256 + threadIdx.x;   // 0..16383
    int j    = o & 7;
    int lane = (o >> 3) & 63;
    int frag = o >> 9;                        // 0..31
    int ntile = frag >> 2, ktile = frag & 3;
    int n = ntile * 16 + (lane & 15);
    int k = ktile * 32 + (lane >> 4) * 8 + j;
    w1f[o] = (_Float16)w1[k * D + n];
    w2f[o] = (_Float16)w2[k * D + n];
}

// ---------------------------------------------------------------------------
// K1: xw = (x @ w1) * inter_nw via MFMA (transposed-operand epilogue).
// Output layout: SLICE-MAJOR xws[8][ND][16] halfs (32 B rows per slice) so
// each gather_e block touches only one 3.2 MB slice (per-XCD L2-resident).
// ---------------------------------------------------------------------------
__global__ __launch_bounds__(256) void k_xw(const float* __restrict__ x,
                                            const _Float16* __restrict__ w1f_g,
                                            const float* __restrict__ inter_p,
                                            _Float16* __restrict__ xws) {
    __shared__ _Float16 wfrag[D * D];     // 32 KB, fragment-major
    __shared__ _Float16 xs[64 * APAD];    // 17 KB
    int t = threadIdx.x;
    {
        const float4* src = (const float4*)w1f_g;
        float4* dst = (float4*)wfrag;
        #pragma unroll
        for (int i = 0; i < 8; ++i) dst[i * 256 + t] = src[i * 256 + t];
    }
    int rowbase = blockIdx.x * 64;
    #pragma unroll
    for (int p = 0; p < 8; ++p) {
        int idx = p * 1024 + t * 4;
        int r = idx >> 7, c = idx & 127;
        int grow = rowbase + r;
        float4 v = make_float4(0.f, 0.f, 0.f, 0.f);
        if (grow < ND) v = ((const float4*)x)[(size_t)grow * 32 + (c >> 2)];
        half4_t h = { (_Float16)v.x, (_Float16)v.y, (_Float16)v.z, (_Float16)v.w };
        *(half4_t*)&xs[r * APAD + c] = h;
    }
    __syncthreads();

    int wave = t >> 6, lane = t & 63;
    int quad = lane >> 4, l15 = lane & 15;
    int m0 = wave * 16;
    float inter = inter_p[0];

    half8_t a[4];
    #pragma unroll
    for (int kt = 0; kt < 4; ++kt)
        a[kt] = *(const half8_t*)&xs[(m0 + l15) * APAD + kt * 32 + quad * 8];

    int grow = rowbase + m0 + l15;
    #pragma unroll
    for (int nt = 0; nt < 8; ++nt) {
        f32x4_t acc = {0.f, 0.f, 0.f, 0.f};
        #pragma unroll
        for (int kt = 0; kt < 4; ++kt) {
            half8_t b = *(const half8_t*)&wfrag[((nt * 4 + kt) * 64 + lane) * 8];
            acc = __builtin_amdgcn_mfma_f32_16x16x32_f16(b, a[kt], acc, 0, 0, 0);
        }
        half4_t hv = { (_Float16)(acc[0] * inter), (_Float16)(acc[1] * inter),
                       (_Float16)(acc[2] * inter), (_Float16)(acc[3] * inter) };
        if (grow < ND)   // slice nt, row grow, cols quad*4..+4
            *(half4_t*)(xws + ((size_t)nt * ND + grow) * 16 + quad * 4) = hv;
    }
}

// ---------------------------------------------------------------------------
// K2a: edge gather, XCD-pinned slice s = blockIdx&7. ZERO LDS.
// 128 edges/block = 256 thr: lane pair (2k,2k+1) owns edge k's two 16-B
// chunks. Each lane loads its chunk's 16 slot indices; phase 2 broadcasts
// slot tt via __shfl from lane 2*e2l + (tt>>4) (broadcast-2, conflict-free).
// ---------------------------------------------------------------------------
__global__ __launch_bounds__(256) void k_gather_e(const int* __restrict__ seq,
                                                  const _Float16* __restrict__ xws,
                                                  _Float16* __restrict__ ea) {
    int t = threadIdx.x;
    int s = blockIdx.x & 7;
    int g = blockIdx.x >> 3;
    int eg0 = g * EPB;
    int lane = t & 63;
    int e2l = lane >> 1;          // local edge within wave, 0..31
    int chunk = lane & 1;         // which 16 B of the 32 B slice row
    int e2 = (t >> 6) * 32 + e2l; // edge in block, 0..127  (== t>>1)
    int eg = eg0 + e2;

    int egs = min(eg, NE - 1);
    const int4* sp = (const int4*)(seq + (size_t)egs * AR + chunk * 16);
    int4 a = sp[0], b = sp[1], c = sp[2], d = sp[3];
    int idxs[16] = { a.x, a.y, a.z, a.w, b.x, b.y, b.z, b.w,
                     c.x, c.y, c.z, c.w, d.x, d.y, d.z, d.w };
    int pc = 0;
    #pragma unroll
    for (int j = 0; j < 16; ++j) pc += (idxs[j] > 0);
    int cnt = __shfl(pc, 2 * e2l, 64) + __shfl(pc, 2 * e2l + 1, 64);
    bool allv = (cnt == 0);
    float wv = 1.f / (float)(allv ? AR : cnt);

    const _Float16* tab = xws + (size_t)s * ND * 16 + chunk * 8;
    float acc[8] = {};
    #pragma unroll
    for (int tt = 0; tt < AR; ++tt) {
        int srow = __shfl(idxs[tt & 15], 2 * e2l + (tt >> 4), 64);
        float w = (allv | (srow > 0)) ? wv : 0.f;
        half8_t v = *(const half8_t*)(tab + (size_t)srow * 16);
        #pragma unroll
        for (int jj = 0; jj < 8; ++jj)
            acc[jj] = fmaf(w, (float)v[jj], acc[jj]);
    }
    if (eg < NE) {
        half8_t h;
        #pragma unroll
        for (int jj = 0; jj < 8; ++jj) h[jj] = (_Float16)fmaxf(acc[jj], 0.f);
        *(half8_t*)(ea + (size_t)eg * D + s * 16 + chunk * 8) = h;
    }
}

// ---------------------------------------------------------------------------
// K2b: e1 = ea @ w2 via MFMA; output SLICE-MAJOR e1s[4][NE][32] halfs
// (64 B rows per slice, 3.2 MB/slice) for the sliced node gather.
// ---------------------------------------------------------------------------
__global__ __launch_bounds__(256) void k_gemm_e(const _Float16* __restrict__ ea,
                                                const _Float16* __restrict__ w2f_g,
                                                _Float16* __restrict__ e1s) {
    __shared__ _Float16 wfrag[D * D];
    __shared__ _Float16 et[64 * APAD];
    int t = threadIdx.x;
    {
        const float4* src = (const float4*)w2f_g;
        float4* dst = (float4*)wfrag;
        #pragma unroll
        for (int i = 0; i < 8; ++i) dst[i * 256 + t] = src[i * 256 + t];
    }
    int rowbase = blockIdx.x * 64;
    #pragma unroll
    for (int p = 0; p < 4; ++p) {
        int hidx = p * 2048 + t * 8;
        int r = hidx >> 7, c = hidx & 127;
        int grow = rowbase + r;
        int gs = (grow < NE) ? grow : (NE - 1);
        half8_t v = *(const half8_t*)(ea + (size_t)gs * D + c);
        *(half8_t*)&et[r * APAD + c] = v;
    }
    __syncthreads();

    int wave = t >> 6, lane = t & 63;
    int quad = lane >> 4, l15 = lane & 15;
    int m0 = wave * 16;

    half8_t a[4];
    #pragma unroll
    for (int kt = 0; kt < 4; ++kt)
        a[kt] = *(const half8_t*)&et[(m0 + l15) * APAD + kt * 32 + quad * 8];

    int grow = rowbase + m0 + l15;
    #pragma unroll
    for (int nt = 0; nt < 8; ++nt) {
        f32x4_t acc = {0.f, 0.f, 0.f, 0.f};
        #pragma unroll
        for (int kt = 0; kt < 4; ++kt) {
            half8_t b = *(const half8_t*)&wfrag[((nt * 4 + kt) * 64 + lane) * 8];
            acc = __builtin_amdgcn_mfma_f32_16x16x32_f16(b, a[kt], acc, 0, 0, 0);
        }
        half4_t hv = { (_Float16)acc[0], (_Float16)acc[1],
                       (_Float16)acc[2], (_Float16)acc[3] };
        if (grow < NE)   // slice nt>>1, col-in-slice (nt&1)*16 + quad*4
            *(half4_t*)(e1s + ((size_t)(nt >> 1) * NE + grow) * 32
                            + (nt & 1) * 16 + quad * 4) = hv;
    }
}

// ---------------------------------------------------------------------------
// K3: node gather, XCD-pinned slice s = blockIdx&3. ZERO LDS.
// 64 nodes/block = 256 thr: lane quad (4k..4k+3) owns node k's four 16-B
// chunks of the 64 B slice row. Slot tt via __shfl from lane 4*n2l+(tt>>2).
// Output: chunk covers 8 cols -> float offset s*32 + chunk*8.
// ---------------------------------------------------------------------------
__global__ __launch_bounds__(256) void k_gather_n(const int* __restrict__ useq,
                                                  const _Float16* __restrict__ e1s,
                                                  float* __restrict__ out) {
    int t = threadIdx.x;
    int s = blockIdx.x & 3;
    int g = blockIdx.x >> 2;
    int ng0 = g * 64;
    int lane = t & 63;
    int n2l = lane >> 2;          // local node within wave, 0..15
    int chunk = lane & 3;         // which 16 B of the 64 B slice row
    int n2 = (t >> 6) * 16 + n2l; // node in block, 0..63  (== t>>2)
    int ng = ng0 + n2;

    int ns = min(ng, ND - 1);
    int4 a = *(const int4*)(useq + (size_t)ns * DG + chunk * 4);
    int idxs[4] = { a.x, a.y, a.z, a.w };
    int pc = (a.x > 0) + (a.y > 0) + (a.z > 0) + (a.w > 0);
    int cnt = __shfl(pc, 4 * n2l, 64)     + __shfl(pc, 4 * n2l + 1, 64)
            + __shfl(pc, 4 * n2l + 2, 64) + __shfl(pc, 4 * n2l + 3, 64);
    bool allv = (cnt == 0);
    float wv = 1.f / (float)(allv ? DG : cnt);

    const _Float16* tab = e1s + (size_t)s * NE * 32 + chunk * 8;
    float acc[8] = {};
    #pragma unroll
    for (int tt = 0; tt < DG; ++tt) {
        int srow = __shfl(idxs[tt & 3], 4 * n2l + (tt >> 2), 64);
        float w = (allv | (srow > 0)) ? wv : 0.f;
        half8_t v = *(const half8_t*)(tab + (size_t)srow * 32);
        #pragma unroll
        for (int jj = 0; jj < 8; ++jj)
            acc[jj] = fmaf(w, (float)v[jj], acc[jj]);
    }
    if (ng < ND) {
        f32x4_t o0 = { acc[0], acc[1], acc[2], acc[3] };
        f32x4_t o1 = { acc[4], acc[5], acc[6], acc[7] };
        f32x4_t* p = (f32x4_t*)(out + (size_t)ng * D + s * 32 + chunk * 8);
        __builtin_nontemporal_store(o0, p);
        __builtin_nontemporal_store(o1, p + 1);
    }
}

// ---------------------------------------------------------------------------
extern "C" void kernel_launch(void* const* d_in, const int* in_sizes, int n_in,
                              void* d_out, int out_size, void* d_ws, size_t ws_size,
                              hipStream_t stream) {
    const float* x    = (const float*)d_in[0];
    const int*   seq  = (const int*)d_in[1];
    const int*   useq = (const int*)d_in[2];
    // d_in[3] = TextVector: unused (reference overwrites it with weight3[0])
    const float* w1   = (const float*)d_in[4];
    const float* w2   = (const float*)d_in[5];
    const float* w3   = (const float*)d_in[6];
    float* out = (float*)d_out;

    // Scratch: d_out hosts xws [0,25.6M) and ea [25.6M,38.4M) (dead before
    // k_gather_n overwrites d_out). d_ws: inter | w1f 32K | w2f 32K | e1s 12.8M.
    _Float16* xws   = (_Float16*)d_out;
    _Float16* ea    = (_Float16*)d_out + (size_t)ND * D;
    float*    inter = (float*)d_ws;
    _Float16* w1f   = (_Float16*)((char*)d_ws + 256);
    _Float16* w2f   = (_Float16*)((char*)d_ws + 256 + 32768);
    _Float16* e1s   = (_Float16*)((char*)d_ws + 256 + 65536);

    int eg_grp = (NE + EPB - 1) / EPB;   // 391
    int ng_grp = (ND + 63) / 64;         // 1563

    hipLaunchKernelGGL(k_prep,     dim3(65),             dim3(256), 0, stream, w1, w2, w3, w1f, w2f, inter);
    hipLaunchKernelGGL(k_xw,       dim3((ND + 63) / 64), dim3(256), 0, stream, x, w1f, inter, xws);
    hipLaunchKernelGGL(k_gather_e, dim3(eg_grp * 8),     dim3(256), 0, stream, seq, xws, ea);
    hipLaunchKernelGGL(k_gemm_e,   dim3((NE + 63) / 64), dim3(256), 0, stream, ea, w2f, e1s);
    hipLaunchKernelGGL(k_gather_n, dim3(ng_grp * 4),     dim3(256), 0, stream, useq, e1s, out);
}